// Round 1
// baseline (3060.833 us; speedup 1.0000x reference)
//
#include <hip/hip_runtime.h>
#include <stdint.h>

// Problem constants
#define PB 256
#define PT 64
#define PE 300
#define PH 512
#define PDA 350
#define PR 16
#define PS 64
#define PA 16

typedef __attribute__((ext_vector_type(8))) short short8;
typedef __attribute__((ext_vector_type(4))) float f4;

__device__ __forceinline__ float bf2f(unsigned short u) {
    unsigned v = ((unsigned)u) << 16;
    return __builtin_bit_cast(float, v);
}
__device__ __forceinline__ unsigned short f2bf(float f) {
    unsigned u = __builtin_bit_cast(unsigned int, f);
    u = u + 0x7fffu + ((u >> 16) & 1u);
    return (unsigned short)(u >> 16);
}
__device__ __forceinline__ float sigf(float x) { return 1.f / (1.f + __expf(-x)); }
__device__ __forceinline__ float tanhf_(float x) { return 1.f - 2.f / (1.f + __expf(2.f * x)); }

// ---------------- converters ----------------

// x[t][b][e] = embedding[tokens[b][t]][e], bf16, K padded 300->320
__global__ __launch_bounds__(256) void k_embed(const int* __restrict__ tokens,
                                               const float* __restrict__ emb,
                                               unsigned short* __restrict__ X) {
    int idx = blockIdx.x * 256 + threadIdx.x;
    if (idx >= 16384 * 320) return;
    int row = idx / 320, e = idx - row * 320;
    int t = row >> 8, b = row & 255;
    float v = 0.f;
    if (e < 300) v = emb[(long)tokens[b * 64 + t] * 300 + e];
    X[idx] = f2bf(v);
}

// fp32 [N][K] -> bf16 [N2][K2] zero padded
__global__ __launch_bounds__(256) void k_cvt_pad(const float* __restrict__ src,
                                                 unsigned short* __restrict__ dst,
                                                 int N, int K, int N2, int K2) {
    int idx = blockIdx.x * 256 + threadIdx.x;
    if (idx >= N2 * K2) return;
    int n = idx / K2, k = idx - n * K2;
    float v = (n < N && k < K) ? src[(long)n * K + k] : 0.f;
    dst[idx] = f2bf(v);
}

// caps_W [16][1024][1024] fp32 -> capsT [16][n][k] bf16 (transpose last two)
__global__ __launch_bounds__(256) void k_capsT(const float* __restrict__ src,
                                               unsigned short* __restrict__ dst) {
    __shared__ float tile[32][33];
    int r = blockIdx.x, kb = blockIdx.y * 32, nb = blockIdx.z * 32;
    int tx = threadIdx.x & 31, ty = threadIdx.x >> 5; // ty 0..7
    for (int i = 0; i < 32; i += 8)
        tile[ty + i][tx] = src[((long)r << 20) + (long)(kb + ty + i) * 1024 + nb + tx];
    __syncthreads();
    for (int i = 0; i < 32; i += 8)
        dst[((long)r << 20) + (long)(nb + ty + i) * 1024 + kb + tx] = f2bf(tile[tx][ty + i]);
}

// Whh [2048][512] fp32 -> fragment-order bf16 image [16 hs][8 nt][16 ks][64 lane][8 el]
__global__ __launch_bounds__(256) void k_whh_shuf(const float* __restrict__ W,
                                                  unsigned short* __restrict__ dst) {
    int idx = blockIdx.x * 256 + threadIdx.x; // 1048576 total
    int el = idx & 7, lane = (idx >> 3) & 63, ks = (idx >> 9) & 15, nt = (idx >> 13) & 7, hs = idx >> 16;
    int gcol = (nt >> 1) * 512 + hs * 32 + (nt & 1) * 16 + (lane & 15);
    int k = ks * 32 + (lane >> 4) * 8 + el;
    dst[idx] = f2bf(W[(long)gcol * 512 + k]);
}

// ---------------- generic bf16 MFMA GEMM:  C[m][n] = sum_k A[m][k]*W[n][k] (+bias) ----------------
template <int OUT_BF16, int TANH>
__global__ __launch_bounds__(256) void k_gemm(const unsigned short* __restrict__ A,
                                              const unsigned short* __restrict__ W,
                                              void* __restrict__ Cv,
                                              const float* __restrict__ bias,
                                              int K, int lda, int ldc,
                                              long aOffZ, long wOffZ, long cOffZ, long bOffZ) {
    A += blockIdx.z * aOffZ;
    W += blockIdx.z * wOffZ;
    if (bias) bias += blockIdx.z * bOffZ;
    const long cbase = blockIdx.z * cOffZ;
    const int m0 = blockIdx.x * 128, n0 = blockIdx.y * 128;
    __shared__ unsigned short As[4096], Bs[4096];
    const int w = threadIdx.x >> 6, l = threadIdx.x & 63;
    const int wm = w & 1, wn = w >> 1;
    const int fr = l & 15, fk = (l >> 4) * 8;
    f4 acc[4][4] = {};
    for (int k0 = 0; k0 < K; k0 += 32) {
        __syncthreads();
#pragma unroll
        for (int i = 0; i < 2; i++) {
            int tI = w + i * 4;
            const unsigned short* ga = A + (long)(m0 + tI * 16 + fr) * lda + k0 + fk;
            const unsigned short* gb = W + (long)(n0 + tI * 16 + fr) * K + k0 + fk;
            *(short8*)&As[tI * 512 + l * 8] = *(const short8*)ga;
            *(short8*)&Bs[tI * 512 + l * 8] = *(const short8*)gb;
        }
        __syncthreads();
        short8 av[4], bv[4];
#pragma unroll
        for (int mt = 0; mt < 4; mt++) av[mt] = *(short8*)&As[(wm * 4 + mt) * 512 + l * 8];
#pragma unroll
        for (int nt = 0; nt < 4; nt++) bv[nt] = *(short8*)&Bs[(wn * 4 + nt) * 512 + l * 8];
#pragma unroll
        for (int mt = 0; mt < 4; mt++)
#pragma unroll
            for (int nt = 0; nt < 4; nt++)
                acc[mt][nt] = __builtin_amdgcn_mfma_f32_16x16x32_bf16(av[mt], bv[nt], acc[mt][nt], 0, 0, 0);
    }
#pragma unroll
    for (int mt = 0; mt < 4; mt++) {
        int row = m0 + wm * 64 + mt * 16 + (l >> 4) * 4;
#pragma unroll
        for (int nt = 0; nt < 4; nt++) {
            int col = n0 + wn * 64 + nt * 16 + (l & 15);
            float bb = bias ? bias[col] : 0.f;
#pragma unroll
            for (int i = 0; i < 4; i++) {
                float v = acc[mt][nt][i] + bb;
                if (TANH) v = tanhf_(v);
                long off = cbase + (long)(row + i) * ldc + col;
                if (OUT_BF16)
                    ((unsigned short*)Cv)[off] = f2bf(v);
                else
                    ((float*)Cv)[off] = v;
            }
        }
    }
}

// ---------------- persistent bidirectional LSTM layer ----------------
// grid = 128 blocks: dir(2) x bg(4, 64 batch rows) x hs(16, 32 h-cols)
// Zx: bf16 [2 dir][64 t][256 b][2048 gates] (bias already folded in)
// Wshuf: bf16 [2 dir][16 hs][8 nt][16 ks][64][8]
// hbuf: bf16 [2 parity][2 dir][256][512]
// Lout: bf16 [64*256][1024] (row = t*256+b, col = dir*512 + j)
__global__ __launch_bounds__(256) void k_lstm(const unsigned short* __restrict__ Zx,
                                              const unsigned short* __restrict__ Wshuf,
                                              unsigned short* __restrict__ hbuf,
                                              unsigned short* __restrict__ Lout,
                                              unsigned* __restrict__ cnt) {
    extern __shared__ char smem[];
    unsigned short* Wl = (unsigned short*)smem;        // 65536 el = 128 KB
    float* zl = (float*)(smem + 131072);               // [32][132] = 16.9 KB
    const int bid = blockIdx.x;
    const int dir = bid >> 6, bg = (bid >> 4) & 3, hs = bid & 15;
    const int tid = threadIdx.x;
    const int l = tid & 63;
    const int w = tid >> 6;
    const int mt2 = w & 1, hc2 = w >> 1;

    // load this block's Whh fragment slice into LDS (resident for all 64 steps)
    {
        const short8* src = (const short8*)(Wshuf + ((long)(dir * 16 + hs) << 16));
        short8* dst = (short8*)Wl;
        for (int i = tid; i < 8192; i += 256) dst[i] = src[i];
    }
    // zero h parity 0 (this block's write slice)
    {
        unsigned short* hz = hbuf + (long)dir * 256 * 512;
        for (int i = tid; i < 1024; i += 256) {
            int r = i >> 4, c2 = i & 15;
            *(unsigned*)&hz[(bg * 64 + r) * 512 + hs * 32 + c2 * 2] = 0u;
        }
    }
    unsigned* myc = cnt + (dir * 4 + bg);
    __syncthreads();
    if (tid == 0) { __threadfence(); atomicAdd(myc, 1u); }

    float c_reg[8];
#pragma unroll
    for (int i = 0; i < 8; i++) c_reg[i] = 0.f;

    for (int step = 0; step < 64; step++) {
        if (tid == 0) {
            unsigned target = 16u * (unsigned)(step + 1);
            while (__hip_atomic_load(myc, __ATOMIC_ACQUIRE, __HIP_MEMORY_SCOPE_AGENT) < target)
                __builtin_amdgcn_s_sleep(1);
        }
        __syncthreads();
        const int rp = step & 1, wp = rp ^ 1;
        const int t_eff = dir ? (63 - step) : step;

        // GEMM: acc[i2][s] = h(rows of this wave) @ WhhT(slice)
        f4 acc[2][4] = {};
        const unsigned short* hb = hbuf + (long)(rp * 2 + dir) * 256 * 512;
        const int arow0 = (bg * 64 + (mt2 * 2 + 0) * 16 + (l & 15)) * 512;
        const int arow1 = (bg * 64 + (mt2 * 2 + 1) * 16 + (l & 15)) * 512;
        const int akoff = (l >> 4) * 8;
        for (int ks = 0; ks < 16; ks++) {
            short8 a0 = *(const short8*)&hb[arow0 + ks * 32 + akoff];
            short8 a1 = *(const short8*)&hb[arow1 + ks * 32 + akoff];
#pragma unroll
            for (int s = 0; s < 4; s++) {
                int nt = s * 2 + hc2;
                short8 b = *(const short8*)&Wl[((nt * 16 + ks) * 64 + l) * 8];
                acc[0][s] = __builtin_amdgcn_mfma_f32_16x16x32_bf16(a0, b, acc[0][s], 0, 0, 0);
                acc[1][s] = __builtin_amdgcn_mfma_f32_16x16x32_bf16(a1, b, acc[1][s], 0, 0, 0);
            }
        }

        unsigned short* hw = hbuf + (long)(wp * 2 + dir) * 256 * 512;
        const unsigned short* zbase = Zx + ((long)dir * 16384 + (long)t_eff * 256) * 2048;
#pragma unroll
        for (int half = 0; half < 2; half++) {
            __syncthreads();
            if (mt2 == half) {
#pragma unroll
                for (int i2 = 0; i2 < 2; i2++) {
                    int rloc = i2 * 16 + (l >> 4) * 4;
#pragma unroll
                    for (int s = 0; s < 4; s++) {
                        int col = s * 32 + hc2 * 16 + (l & 15);
#pragma unroll
                        for (int i = 0; i < 4; i++) zl[(rloc + i) * 132 + col] = acc[i2][s][i];
                    }
                }
            }
            __syncthreads();
#pragma unroll
            for (int k = 0; k < 4; k++) {
                int p = k * 256 + tid;
                int r = p >> 5, j32 = p & 31;
                int rowg = bg * 64 + half * 32 + r;
                int jg = hs * 32 + j32;
                const unsigned short* zrow = zbase + (long)rowg * 2048;
                float zi = zl[r * 132 + 0 * 32 + j32] + bf2f(zrow[0 * 512 + jg]);
                float zf = zl[r * 132 + 1 * 32 + j32] + bf2f(zrow[1 * 512 + jg]);
                float zg = zl[r * 132 + 2 * 32 + j32] + bf2f(zrow[2 * 512 + jg]);
                float zo = zl[r * 132 + 3 * 32 + j32] + bf2f(zrow[3 * 512 + jg]);
                int ci = half * 4 + k;
                float c = sigf(zf) * c_reg[ci] + sigf(zi) * tanhf_(zg);
                c_reg[ci] = c;
                float h = sigf(zo) * tanhf_(c);
                unsigned short hb16 = f2bf(h);
                hw[rowg * 512 + jg] = hb16;
                Lout[((long)t_eff * 256 + rowg) * 1024 + dir * 512 + jg] = hb16;
            }
        }
        __syncthreads();
        if (tid == 0) { __threadfence(); atomicAdd(myc, 1u); }
    }
}

// ---------------- alphas: att[b][r][t] = sum_k hbar[bt][k]*ws2[r][k] ----------------
__global__ __launch_bounds__(256) void k_alphas(const unsigned short* __restrict__ hbar,
                                                const unsigned short* __restrict__ ws2,
                                                float* __restrict__ att) {
    int w = threadIdx.x >> 6, l = threadIdx.x & 63;
    int mtile = blockIdx.x * 4 + w;
    f4 acc = {};
    const unsigned short* arow = hbar + (long)(mtile * 16 + (l & 15)) * 384 + (l >> 4) * 8;
    const unsigned short* brow = ws2 + (long)(l & 15) * 384 + (l >> 4) * 8;
    for (int ks = 0; ks < 12; ks++) {
        short8 a = *(const short8*)&arow[ks * 32];
        short8 b = *(const short8*)&brow[ks * 32];
        acc = __builtin_amdgcn_mfma_f32_16x16x32_bf16(a, b, acc, 0, 0, 0);
    }
    int r = l & 15;
#pragma unroll
    for (int i = 0; i < 4; i++) {
        int bt = mtile * 16 + (l >> 4) * 4 + i;
        int b = bt & 255, t = bt >> 8;
        att[((long)b * 16 + r) * 64 + t] = acc[i];
    }
}

// ---------------- sent[b][r][n] = sum_t att[b][r][t]*outp[b][t][n] ----------------
__global__ __launch_bounds__(256) void k_sent(const float* __restrict__ att,
                                              const unsigned short* __restrict__ L1,
                                              float* __restrict__ sent,
                                              unsigned short* __restrict__ sentb) {
    int b = blockIdx.x, n0 = blockIdx.y * 128;
    __shared__ float al[1024];
    for (int i = threadIdx.x; i < 1024; i += 256) al[i] = att[(long)b * 1024 + i];
    __syncthreads();
#pragma unroll
    for (int k = 0; k < 8; k++) {
        int item = k * 256 + threadIdx.x;
        int n = n0 + (item & 127), r = item >> 7;
        float s = 0.f;
        for (int t = 0; t < 64; t++) s += al[r * 64 + t] * bf2f(L1[((long)t * 256 + b) * 1024 + n]);
        long o = ((long)b * 16 + r) * 1024 + n;
        sent[o] = s;
        sentb[o] = f2bf(s);
    }
}

// ---------------- dynamic routing, one block per batch ----------------
__global__ __launch_bounds__(256) void k_route(const float* __restrict__ votes,
                                               float* __restrict__ clog) {
    __shared__ float v[16384];
    __shared__ float logits[1024];
    __shared__ float route[1024];
    __shared__ float pre[1024];
    __shared__ float act[1024];
    __shared__ float cl[64];
    int b = blockIdx.x, tid = threadIdx.x;
    for (int i = tid; i < 4096; i += 256) ((f4*)v)[i] = ((const f4*)(votes + (long)b * 16384))[i];
    for (int i = tid; i < 1024; i += 256) logits[i] = 0.f;
    __syncthreads();
    for (int it = 0; it < 3; it++) {
        if (tid < 16) {
            float m = -1e30f;
            for (int s = 0; s < 64; s++) m = fmaxf(m, logits[tid * 64 + s]);
            float sum = 0.f;
            for (int s = 0; s < 64; s++) {
                float e = __expf(logits[tid * 64 + s] - m);
                route[tid * 64 + s] = e;
                sum += e;
            }
            float inv = 1.f / sum;
            for (int s = 0; s < 64; s++) route[tid * 64 + s] *= inv;
        }
        __syncthreads();
#pragma unroll
        for (int k = 0; k < 4; k++) {
            int p = k * 256 + tid;
            int s = p >> 4, a = p & 15;
            float acc = 0.f;
            for (int r = 0; r < 16; r++) acc += route[r * 64 + s] * v[(r * 64 + s) * 16 + a];
            pre[p] = acc;
        }
        __syncthreads();
        if (tid < 64) {
            float nsq = 0.f;
            for (int a = 0; a < 16; a++) nsq += pre[tid * 16 + a] * pre[tid * 16 + a];
            float norm = sqrtf(nsq);
            float sc = norm / (0.5f + nsq);
            for (int a = 0; a < 16; a++) act[tid * 16 + a] = pre[tid * 16 + a] * sc;
            cl[tid] = nsq / (0.5f + nsq);
        }
        __syncthreads();
#pragma unroll
        for (int k = 0; k < 4; k++) {
            int p = k * 256 + tid;
            int r = p >> 6, s = p & 63;
            float acc = 0.f;
            for (int a = 0; a < 16; a++) acc += v[(r * 64 + s) * 16 + a] * act[s * 16 + a];
            logits[p] += acc;
        }
        __syncthreads();
    }
    if (tid < 64) clog[(long)b * 64 + tid] = cl[tid];
}

// ---------------- host ----------------
extern "C" void kernel_launch(void* const* d_in, const int* in_sizes, int n_in,
                              void* d_out, int out_size, void* d_ws, size_t ws_size,
                              hipStream_t stream) {
    const int* tokens = (const int*)d_in[0];
    const float* embedding = (const float*)d_in[2];
    const float* Wih_l0f = (const float*)d_in[3];
    const float* Whh_l0f = (const float*)d_in[4];
    const float* b_l0f = (const float*)d_in[5];
    const float* Wih_l0b = (const float*)d_in[6];
    const float* Whh_l0b = (const float*)d_in[7];
    const float* b_l0b = (const float*)d_in[8];
    const float* Wih_l1f = (const float*)d_in[9];
    const float* Whh_l1f = (const float*)d_in[10];
    const float* b_l1f = (const float*)d_in[11];
    const float* Wih_l1b = (const float*)d_in[12];
    const float* Whh_l1b = (const float*)d_in[13];
    const float* b_l1b = (const float*)d_in[14];
    const float* ws1 = (const float*)d_in[15];
    const float* ws2 = (const float*)d_in[16];
    const float* caps_W = (const float*)d_in[17];
    float* out = (float*)d_out;

    char* ws = (char*)d_ws;
    size_t o = 0;
    unsigned short* Xb16 = (unsigned short*)(ws + o); o += (size_t)16384 * 320 * 2;
    unsigned short* ZxL = (unsigned short*)(ws + o); size_t zx_off = o; o += (size_t)2 * 16384 * 2048 * 2;
    unsigned short* L0 = (unsigned short*)(ws + o); o += (size_t)16384 * 1024 * 2;
    unsigned short* L1 = (unsigned short*)(ws + o); o += (size_t)16384 * 1024 * 2;
    unsigned short* Wl0b = (unsigned short*)(ws + o); o += (size_t)2 * 2048 * 320 * 2;
    unsigned short* Wl1b = (unsigned short*)(ws + o); o += (size_t)2 * 2048 * 1024 * 2;
    unsigned short* Wsh0 = (unsigned short*)(ws + o); o += (size_t)2 * 1048576 * 2;
    unsigned short* Wsh1 = (unsigned short*)(ws + o); o += (size_t)2 * 1048576 * 2;
    unsigned short* ws1b = (unsigned short*)(ws + o); o += (size_t)384 * 1024 * 2;
    unsigned short* ws2b = (unsigned short*)(ws + o); o += (size_t)16 * 384 * 2 + 192; // keep align
    unsigned short* capsT = (unsigned short*)(ws + o); o += (size_t)16 * 1024 * 1024 * 2;
    unsigned short* hbuf = (unsigned short*)(ws + o); o += (size_t)2 * 2 * 256 * 512 * 2;
    float* biasc = (float*)(ws + o); o += (size_t)4 * 2048 * 4;
    unsigned* cnts = (unsigned*)(ws + o); o += 256;
    // overlay region (inside ZxL, which is dead after layer-1 recurrence):
    unsigned short* hbarb = (unsigned short*)(ws + zx_off);
    float* att = (float*)(ws + zx_off + (size_t)16384 * 384 * 2);
    unsigned short* sentb = (unsigned short*)(ws + zx_off + (size_t)16384 * 384 * 2 + 1048576);
    float* votes = (float*)(ws + zx_off + (size_t)16384 * 384 * 2 + 1048576 + (size_t)256 * 16 * 1024 * 2);

    hipMemsetAsync(cnts, 0, 256, stream);

    // converters
    k_embed<<<16384 * 320 / 256, 256, 0, stream>>>(tokens, embedding, Xb16);
    k_cvt_pad<<<(2048 * 320 + 255) / 256, 256, 0, stream>>>(Wih_l0f, Wl0b, 2048, 300, 2048, 320);
    k_cvt_pad<<<(2048 * 320 + 255) / 256, 256, 0, stream>>>(Wih_l0b, Wl0b + (size_t)2048 * 320, 2048, 300, 2048, 320);
    k_cvt_pad<<<(2048 * 1024 + 255) / 256, 256, 0, stream>>>(Wih_l1f, Wl1b, 2048, 1024, 2048, 1024);
    k_cvt_pad<<<(2048 * 1024 + 255) / 256, 256, 0, stream>>>(Wih_l1b, Wl1b + (size_t)2048 * 1024, 2048, 1024, 2048, 1024);
    k_cvt_pad<<<(384 * 1024 + 255) / 256, 256, 0, stream>>>(ws1, ws1b, 350, 1024, 384, 1024);
    k_cvt_pad<<<(16 * 384 + 255) / 256, 256, 0, stream>>>(ws2, ws2b, 16, 350, 16, 384);
    k_capsT<<<dim3(16, 32, 32), 256, 0, stream>>>(caps_W, capsT);
    k_whh_shuf<<<4096, 256, 0, stream>>>(Whh_l0f, Wsh0);
    k_whh_shuf<<<4096, 256, 0, stream>>>(Whh_l0b, Wsh0 + 1048576);
    k_whh_shuf<<<4096, 256, 0, stream>>>(Whh_l1f, Wsh1);
    k_whh_shuf<<<4096, 256, 0, stream>>>(Whh_l1b, Wsh1 + 1048576);
    hipMemcpyAsync(biasc + 0, b_l0f, 2048 * 4, hipMemcpyDeviceToDevice, stream);
    hipMemcpyAsync(biasc + 2048, b_l0b, 2048 * 4, hipMemcpyDeviceToDevice, stream);
    hipMemcpyAsync(biasc + 4096, b_l1f, 2048 * 4, hipMemcpyDeviceToDevice, stream);
    hipMemcpyAsync(biasc + 6144, b_l1b, 2048 * 4, hipMemcpyDeviceToDevice, stream);

    hipFuncSetAttribute(reinterpret_cast<const void*>(k_lstm),
                        hipFuncAttributeMaxDynamicSharedMemorySize, 147968);

    // layer 0 input projection: Zx = X @ Wih_l0^T + b  (bf16 out)
    k_gemm<1, 0><<<dim3(128, 16, 2), 256, 0, stream>>>(
        Xb16, Wl0b, ZxL, biasc, 320, 320, 2048,
        0L, (long)2048 * 320, (long)16384 * 2048, 2048L);
    // layer 0 recurrence
    k_lstm<<<128, 256, 147968, stream>>>(ZxL, Wsh0, hbuf, L0, cnts);
    // layer 1 input projection
    k_gemm<1, 0><<<dim3(128, 16, 2), 256, 0, stream>>>(
        L0, Wl1b, ZxL, biasc + 4096, 1024, 1024, 2048,
        0L, (long)2048 * 1024, (long)16384 * 2048, 2048L);
    // layer 1 recurrence
    k_lstm<<<128, 256, 147968, stream>>>(ZxL, Wsh1, hbuf, L1, cnts + 8);
    // hbar = tanh(outp @ ws1^T), bf16
    k_gemm<1, 1><<<dim3(128, 3, 1), 256, 0, stream>>>(
        L1, ws1b, hbarb, nullptr, 1024, 1024, 384, 0L, 0L, 0L, 0L);
    // alphas -> att[b][r][t]
    k_alphas<<<256, 256, 0, stream>>>(hbarb, ws2b, att);
    // sent (fp32 to d_out + bf16 copy)
    k_sent<<<dim3(256, 8), 256, 0, stream>>>(att, L1, out, sentb);
    // votes[b][r][s*16+a] = sent[b][r] @ caps_W[r]
    k_gemm<0, 0><<<dim3(2, 8, 16), 256, 0, stream>>>(
        sentb, capsT, votes, nullptr, 1024, 16384, 16384,
        1024L, 1048576L, 1024L, 0L);
    // routing -> class_logits
    k_route<<<256, 256, 0, stream>>>(votes, out + (size_t)4194304);
}

// Round 2
// 2707.542 us; speedup vs baseline: 1.1305x; 1.1305x over previous
//
#include <hip/hip_runtime.h>
#include <stdint.h>

// Problem constants
#define PB 256
#define PT 64
#define PE 300
#define PH 512
#define PDA 350
#define PR 16
#define PS 64
#define PA 16

typedef __attribute__((ext_vector_type(8))) short short8;
typedef __attribute__((ext_vector_type(4))) float f4;
typedef unsigned long long u64;

__device__ __forceinline__ float bf2f(unsigned short u) {
    unsigned v = ((unsigned)u) << 16;
    return __builtin_bit_cast(float, v);
}
__device__ __forceinline__ unsigned short f2bf(float f) {
    unsigned u = __builtin_bit_cast(unsigned int, f);
    u = u + 0x7fffu + ((u >> 16) & 1u);
    return (unsigned short)(u >> 16);
}
__device__ __forceinline__ float sigf(float x) { return 1.f / (1.f + __expf(-x)); }
__device__ __forceinline__ float tanhf_(float x) { return 1.f - 2.f / (1.f + __expf(2.f * x)); }

// ---------------- converters ----------------

__global__ __launch_bounds__(256) void k_embed(const int* __restrict__ tokens,
                                               const float* __restrict__ emb,
                                               unsigned short* __restrict__ X) {
    int idx = blockIdx.x * 256 + threadIdx.x;
    if (idx >= 16384 * 320) return;
    int row = idx / 320, e = idx - row * 320;
    int t = row >> 8, b = row & 255;
    float v = 0.f;
    if (e < 300) v = emb[(long)tokens[b * 64 + t] * 300 + e];
    X[idx] = f2bf(v);
}

__global__ __launch_bounds__(256) void k_cvt_pad(const float* __restrict__ src,
                                                 unsigned short* __restrict__ dst,
                                                 int N, int K, int N2, int K2) {
    int idx = blockIdx.x * 256 + threadIdx.x;
    if (idx >= N2 * K2) return;
    int n = idx / K2, k = idx - n * K2;
    float v = (n < N && k < K) ? src[(long)n * K + k] : 0.f;
    dst[idx] = f2bf(v);
}

__global__ __launch_bounds__(256) void k_capsT(const float* __restrict__ src,
                                               unsigned short* __restrict__ dst) {
    __shared__ float tile[32][33];
    int r = blockIdx.x, kb = blockIdx.y * 32, nb = blockIdx.z * 32;
    int tx = threadIdx.x & 31, ty = threadIdx.x >> 5;
    for (int i = 0; i < 32; i += 8)
        tile[ty + i][tx] = src[((long)r << 20) + (long)(kb + ty + i) * 1024 + nb + tx];
    __syncthreads();
    for (int i = 0; i < 32; i += 8)
        dst[((long)r << 20) + (long)(nb + ty + i) * 1024 + kb + tx] = f2bf(tile[tx][ty + i]);
}

__global__ __launch_bounds__(256) void k_whh_shuf(const float* __restrict__ W,
                                                  unsigned short* __restrict__ dst) {
    int idx = blockIdx.x * 256 + threadIdx.x;
    int el = idx & 7, lane = (idx >> 3) & 63, ks = (idx >> 9) & 15, nt = (idx >> 13) & 7, hs = idx >> 16;
    int gcol = (nt >> 1) * 512 + hs * 32 + (nt & 1) * 16 + (lane & 15);
    int k = ks * 32 + (lane >> 4) * 8 + el;
    dst[idx] = f2bf(W[(long)gcol * 512 + k]);
}

// ---------------- generic bf16 MFMA GEMM ----------------
template <int OUT_BF16, int TANH>
__global__ __launch_bounds__(256) void k_gemm(const unsigned short* __restrict__ A,
                                              const unsigned short* __restrict__ W,
                                              void* __restrict__ Cv,
                                              const float* __restrict__ bias,
                                              int K, int lda, int ldc,
                                              long aOffZ, long wOffZ, long cOffZ, long bOffZ) {
    A += blockIdx.z * aOffZ;
    W += blockIdx.z * wOffZ;
    if (bias) bias += blockIdx.z * bOffZ;
    const long cbase = blockIdx.z * cOffZ;
    const int m0 = blockIdx.x * 128, n0 = blockIdx.y * 128;
    __shared__ unsigned short As[4096], Bs[4096];
    const int w = threadIdx.x >> 6, l = threadIdx.x & 63;
    const int wm = w & 1, wn = w >> 1;
    const int fr = l & 15, fk = (l >> 4) * 8;
    f4 acc[4][4] = {};
    for (int k0 = 0; k0 < K; k0 += 32) {
        __syncthreads();
#pragma unroll
        for (int i = 0; i < 2; i++) {
            int tI = w + i * 4;
            const unsigned short* ga = A + (long)(m0 + tI * 16 + fr) * lda + k0 + fk;
            const unsigned short* gb = W + (long)(n0 + tI * 16 + fr) * K + k0 + fk;
            *(short8*)&As[tI * 512 + l * 8] = *(const short8*)ga;
            *(short8*)&Bs[tI * 512 + l * 8] = *(const short8*)gb;
        }
        __syncthreads();
        short8 av[4], bv[4];
#pragma unroll
        for (int mt = 0; mt < 4; mt++) av[mt] = *(short8*)&As[(wm * 4 + mt) * 512 + l * 8];
#pragma unroll
        for (int nt = 0; nt < 4; nt++) bv[nt] = *(short8*)&Bs[(wn * 4 + nt) * 512 + l * 8];
#pragma unroll
        for (int mt = 0; mt < 4; mt++)
#pragma unroll
            for (int nt = 0; nt < 4; nt++)
                acc[mt][nt] = __builtin_amdgcn_mfma_f32_16x16x32_bf16(av[mt], bv[nt], acc[mt][nt], 0, 0, 0);
    }
#pragma unroll
    for (int mt = 0; mt < 4; mt++) {
        int row = m0 + wm * 64 + mt * 16 + (l >> 4) * 4;
#pragma unroll
        for (int nt = 0; nt < 4; nt++) {
            int col = n0 + wn * 64 + nt * 16 + (l & 15);
            float bb = bias ? bias[col] : 0.f;
#pragma unroll
            for (int i = 0; i < 4; i++) {
                float v = acc[mt][nt][i] + bb;
                if (TANH) v = tanhf_(v);
                long off = cbase + (long)(row + i) * ldc + col;
                if (OUT_BF16)
                    ((unsigned short*)Cv)[off] = f2bf(v);
                else
                    ((float*)Cv)[off] = v;
            }
        }
    }
}

// ---------------- persistent bidirectional LSTM layer ----------------
// Flush-free cross-block protocol:
//  - h exchanged via agent-scope RELAXED atomic ops (sc0 sc1: write-through to
//    Infinity Cache, reads bypass the incoherent per-XCD L2s). No threadfence.
//  - writer: stores -> s_waitcnt vmcnt(0) -> s_barrier -> tid0 relaxed atomicAdd
//  - reader: tid0 relaxed poll -> s_barrier -> loads (issued in order after poll)
__global__ __launch_bounds__(256) void k_lstm(const unsigned short* __restrict__ Zx,
                                              const unsigned short* __restrict__ Wshuf,
                                              unsigned short* __restrict__ hbuf,
                                              unsigned short* __restrict__ Lout,
                                              unsigned* __restrict__ cnt) {
    extern __shared__ char smem[];
    unsigned short* Wl = (unsigned short*)smem;        // 128 KB
    float* zl = (float*)(smem + 131072);               // [32][132]
    const int bid = blockIdx.x;
    const int dir = bid >> 6, bg = (bid >> 4) & 3, hs = bid & 15;
    const int tid = threadIdx.x;
    const int l = tid & 63;
    const int w = tid >> 6;
    const int mt2 = w & 1, hc2 = w >> 1;

    // Whh slice into LDS (resident for all 64 steps)
    {
        const short8* src = (const short8*)(Wshuf + ((long)(dir * 16 + hs) << 16));
        short8* dst = (short8*)Wl;
        for (int i = tid; i < 8192; i += 256) dst[i] = src[i];
    }
    // zero h parity 0 (agent stores so readers that bypass L2 see it)
    {
        unsigned short* hz = hbuf + (long)dir * 256 * 512;
        for (int i = tid; i < 1024; i += 256) {
            int r = i >> 4, c2 = i & 15;
            __hip_atomic_store((unsigned*)&hz[(bg * 64 + r) * 512 + hs * 32 + c2 * 2], 0u,
                               __ATOMIC_RELAXED, __HIP_MEMORY_SCOPE_AGENT);
        }
    }
    unsigned* myc = cnt + (dir * 4 + bg);
    asm volatile("s_waitcnt vmcnt(0)" ::: "memory");
    __syncthreads();
    if (tid == 0) __hip_atomic_fetch_add(myc, 1u, __ATOMIC_RELAXED, __HIP_MEMORY_SCOPE_AGENT);

    float c_reg[8];
#pragma unroll
    for (int i = 0; i < 8; i++) c_reg[i] = 0.f;

    // pointwise mapping (fixed across steps): half, k2 in 0..1:
    //   p2 = k2*256+tid, r = p2>>4 (0..31), col pair c0 = (p2&15)*2
    const int pw_r[2] = { tid >> 4, 16 + (tid >> 4) };
    const int pw_c0 = (tid & 15) * 2;

    for (int step = 0; step < 64; step++) {
        const int t_eff = dir ? (63 - step) : step;
        const unsigned short* zbase = Zx + ((long)dir * 16384 + (long)t_eff * 256) * 2048;

        // prefetch Zx gate pairs for this step (independent of h -> issue before poll)
        unsigned zpre[2][2][4];
#pragma unroll
        for (int half = 0; half < 2; half++)
#pragma unroll
            for (int k2 = 0; k2 < 2; k2++) {
                int rowg = bg * 64 + half * 32 + pw_r[k2];
                int jg = hs * 32 + pw_c0;
                const unsigned short* zrow = zbase + (long)rowg * 2048;
#pragma unroll
                for (int g = 0; g < 4; g++)
                    zpre[half][k2][g] = *(const unsigned*)&zrow[g * 512 + jg];
            }

        if (tid == 0) {
            unsigned target = 16u * (unsigned)(step + 1);
            while (__hip_atomic_load(myc, __ATOMIC_RELAXED, __HIP_MEMORY_SCOPE_AGENT) < target) {}
        }
        __syncthreads();
        const int rp = step & 1, wp = rp ^ 1;

        // GEMM: h(rows of this wave) @ WhhT(slice), h via agent 8B loads (bypass L2)
        f4 acc[2][4] = {};
        const unsigned short* hb = hbuf + (long)(rp * 2 + dir) * 256 * 512;
        const int arow0 = (bg * 64 + (mt2 * 2 + 0) * 16 + (l & 15)) * 512;
        const int arow1 = (bg * 64 + (mt2 * 2 + 1) * 16 + (l & 15)) * 512;
        const int akoff = (l >> 4) * 8;
#pragma unroll
        for (int ks = 0; ks < 16; ks++) {
            union { u64 q[2]; short8 s; } a0u, a1u;
            const u64* pa0 = (const u64*)&hb[arow0 + ks * 32 + akoff];
            const u64* pa1 = (const u64*)&hb[arow1 + ks * 32 + akoff];
            a0u.q[0] = __hip_atomic_load(pa0, __ATOMIC_RELAXED, __HIP_MEMORY_SCOPE_AGENT);
            a0u.q[1] = __hip_atomic_load(pa0 + 1, __ATOMIC_RELAXED, __HIP_MEMORY_SCOPE_AGENT);
            a1u.q[0] = __hip_atomic_load(pa1, __ATOMIC_RELAXED, __HIP_MEMORY_SCOPE_AGENT);
            a1u.q[1] = __hip_atomic_load(pa1 + 1, __ATOMIC_RELAXED, __HIP_MEMORY_SCOPE_AGENT);
#pragma unroll
            for (int s = 0; s < 4; s++) {
                int nt = s * 2 + hc2;
                short8 b = *(short8*)&Wl[((nt * 16 + ks) * 64 + l) * 8];
                acc[0][s] = __builtin_amdgcn_mfma_f32_16x16x32_bf16(a0u.s, b, acc[0][s], 0, 0, 0);
                acc[1][s] = __builtin_amdgcn_mfma_f32_16x16x32_bf16(a1u.s, b, acc[1][s], 0, 0, 0);
            }
        }

        unsigned short* hw = hbuf + (long)(wp * 2 + dir) * 256 * 512;
#pragma unroll
        for (int half = 0; half < 2; half++) {
            __syncthreads();
            if (mt2 == half) {
#pragma unroll
                for (int i2 = 0; i2 < 2; i2++) {
                    int rloc = i2 * 16 + (l >> 4) * 4;
#pragma unroll
                    for (int s = 0; s < 4; s++) {
                        int col = s * 32 + hc2 * 16 + (l & 15);
#pragma unroll
                        for (int i = 0; i < 4; i++) zl[(rloc + i) * 132 + col] = acc[i2][s][i];
                    }
                }
            }
            __syncthreads();
#pragma unroll
            for (int k2 = 0; k2 < 2; k2++) {
                int r = pw_r[k2];
                int c0 = pw_c0;
                int rowg = bg * 64 + half * 32 + r;
                int jg = hs * 32 + c0;
                unsigned ui = zpre[half][k2][0], uf = zpre[half][k2][1];
                unsigned ug = zpre[half][k2][2], uo = zpre[half][k2][3];
                float zi0 = zl[r * 132 + 0 * 32 + c0] + bf2f((unsigned short)ui);
                float zf0 = zl[r * 132 + 1 * 32 + c0] + bf2f((unsigned short)uf);
                float zg0 = zl[r * 132 + 2 * 32 + c0] + bf2f((unsigned short)ug);
                float zo0 = zl[r * 132 + 3 * 32 + c0] + bf2f((unsigned short)uo);
                float zi1 = zl[r * 132 + 0 * 32 + c0 + 1] + bf2f((unsigned short)(ui >> 16));
                float zf1 = zl[r * 132 + 1 * 32 + c0 + 1] + bf2f((unsigned short)(uf >> 16));
                float zg1 = zl[r * 132 + 2 * 32 + c0 + 1] + bf2f((unsigned short)(ug >> 16));
                float zo1 = zl[r * 132 + 3 * 32 + c0 + 1] + bf2f((unsigned short)(uo >> 16));
                int ci = half * 4 + k2 * 2;
                float ca = sigf(zf0) * c_reg[ci] + sigf(zi0) * tanhf_(zg0);
                c_reg[ci] = ca;
                float ha = sigf(zo0) * tanhf_(ca);
                float cb = sigf(zf1) * c_reg[ci + 1] + sigf(zi1) * tanhf_(zg1);
                c_reg[ci + 1] = cb;
                float hbv = sigf(zo1) * tanhf_(cb);
                unsigned pack = (unsigned)f2bf(ha) | ((unsigned)f2bf(hbv) << 16);
                __hip_atomic_store((unsigned*)&hw[(long)rowg * 512 + jg], pack,
                                   __ATOMIC_RELAXED, __HIP_MEMORY_SCOPE_AGENT);
                *(unsigned*)&Lout[((long)t_eff * 256 + rowg) * 1024 + dir * 512 + jg] = pack;
            }
        }
        asm volatile("s_waitcnt vmcnt(0)" ::: "memory");
        __syncthreads();
        if (tid == 0) __hip_atomic_fetch_add(myc, 1u, __ATOMIC_RELAXED, __HIP_MEMORY_SCOPE_AGENT);
    }
}

// ---------------- alphas ----------------
__global__ __launch_bounds__(256) void k_alphas(const unsigned short* __restrict__ hbar,
                                                const unsigned short* __restrict__ ws2,
                                                float* __restrict__ att) {
    int w = threadIdx.x >> 6, l = threadIdx.x & 63;
    int mtile = blockIdx.x * 4 + w;
    f4 acc = {};
    const unsigned short* arow = hbar + (long)(mtile * 16 + (l & 15)) * 384 + (l >> 4) * 8;
    const unsigned short* brow = ws2 + (long)(l & 15) * 384 + (l >> 4) * 8;
    for (int ks = 0; ks < 12; ks++) {
        short8 a = *(const short8*)&arow[ks * 32];
        short8 b = *(const short8*)&brow[ks * 32];
        acc = __builtin_amdgcn_mfma_f32_16x16x32_bf16(a, b, acc, 0, 0, 0);
    }
    int r = l & 15;
#pragma unroll
    for (int i = 0; i < 4; i++) {
        int bt = mtile * 16 + (l >> 4) * 4 + i;
        int b = bt & 255, t = bt >> 8;
        att[((long)b * 16 + r) * 64 + t] = acc[i];
    }
}

// ---------------- sent ----------------
__global__ __launch_bounds__(256) void k_sent(const float* __restrict__ att,
                                              const unsigned short* __restrict__ L1,
                                              float* __restrict__ sent,
                                              unsigned short* __restrict__ sentb) {
    int b = blockIdx.x, n0 = blockIdx.y * 128;
    __shared__ float al[1024];
    for (int i = threadIdx.x; i < 1024; i += 256) al[i] = att[(long)b * 1024 + i];
    __syncthreads();
#pragma unroll
    for (int k = 0; k < 8; k++) {
        int item = k * 256 + threadIdx.x;
        int n = n0 + (item & 127), r = item >> 7;
        float s = 0.f;
        for (int t = 0; t < 64; t++) s += al[r * 64 + t] * bf2f(L1[((long)t * 256 + b) * 1024 + n]);
        long o = ((long)b * 16 + r) * 1024 + n;
        sent[o] = s;
        sentb[o] = f2bf(s);
    }
}

// ---------------- dynamic routing ----------------
__global__ __launch_bounds__(256) void k_route(const float* __restrict__ votes,
                                               float* __restrict__ clog) {
    __shared__ float v[16384];
    __shared__ float logits[1024];
    __shared__ float route[1024];
    __shared__ float pre[1024];
    __shared__ float act[1024];
    __shared__ float cl[64];
    int b = blockIdx.x, tid = threadIdx.x;
    for (int i = tid; i < 4096; i += 256) ((f4*)v)[i] = ((const f4*)(votes + (long)b * 16384))[i];
    for (int i = tid; i < 1024; i += 256) logits[i] = 0.f;
    __syncthreads();
    for (int it = 0; it < 3; it++) {
        if (tid < 16) {
            float m = -1e30f;
            for (int s = 0; s < 64; s++) m = fmaxf(m, logits[tid * 64 + s]);
            float sum = 0.f;
            for (int s = 0; s < 64; s++) {
                float e = __expf(logits[tid * 64 + s] - m);
                route[tid * 64 + s] = e;
                sum += e;
            }
            float inv = 1.f / sum;
            for (int s = 0; s < 64; s++) route[tid * 64 + s] *= inv;
        }
        __syncthreads();
#pragma unroll
        for (int k = 0; k < 4; k++) {
            int p = k * 256 + tid;
            int s = p >> 4, a = p & 15;
            float acc = 0.f;
            for (int r = 0; r < 16; r++) acc += route[r * 64 + s] * v[(r * 64 + s) * 16 + a];
            pre[p] = acc;
        }
        __syncthreads();
        if (tid < 64) {
            float nsq = 0.f;
            for (int a = 0; a < 16; a++) nsq += pre[tid * 16 + a] * pre[tid * 16 + a];
            float norm = sqrtf(nsq);
            float sc = norm / (0.5f + nsq);
            for (int a = 0; a < 16; a++) act[tid * 16 + a] = pre[tid * 16 + a] * sc;
            cl[tid] = nsq / (0.5f + nsq);
        }
        __syncthreads();
#pragma unroll
        for (int k = 0; k < 4; k++) {
            int p = k * 256 + tid;
            int r = p >> 6, s = p & 63;
            float acc = 0.f;
            for (int a = 0; a < 16; a++) acc += v[(r * 64 + s) * 16 + a] * act[s * 16 + a];
            logits[p] += acc;
        }
        __syncthreads();
    }
    if (tid < 64) clog[(long)b * 64 + tid] = cl[tid];
}

// ---------------- host ----------------
extern "C" void kernel_launch(void* const* d_in, const int* in_sizes, int n_in,
                              void* d_out, int out_size, void* d_ws, size_t ws_size,
                              hipStream_t stream) {
    const int* tokens = (const int*)d_in[0];
    const float* embedding = (const float*)d_in[2];
    const float* Wih_l0f = (const float*)d_in[3];
    const float* Whh_l0f = (const float*)d_in[4];
    const float* b_l0f = (const float*)d_in[5];
    const float* Wih_l0b = (const float*)d_in[6];
    const float* Whh_l0b = (const float*)d_in[7];
    const float* b_l0b = (const float*)d_in[8];
    const float* Wih_l1f = (const float*)d_in[9];
    const float* Whh_l1f = (const float*)d_in[10];
    const float* b_l1f = (const float*)d_in[11];
    const float* Wih_l1b = (const float*)d_in[12];
    const float* Whh_l1b = (const float*)d_in[13];
    const float* b_l1b = (const float*)d_in[14];
    const float* ws1 = (const float*)d_in[15];
    const float* ws2 = (const float*)d_in[16];
    const float* caps_W = (const float*)d_in[17];
    float* out = (float*)d_out;

    char* ws = (char*)d_ws;
    size_t o = 0;
    unsigned short* Xb16 = (unsigned short*)(ws + o); o += (size_t)16384 * 320 * 2;
    unsigned short* ZxL = (unsigned short*)(ws + o); size_t zx_off = o; o += (size_t)2 * 16384 * 2048 * 2;
    unsigned short* L0 = (unsigned short*)(ws + o); o += (size_t)16384 * 1024 * 2;
    unsigned short* L1 = (unsigned short*)(ws + o); o += (size_t)16384 * 1024 * 2;
    unsigned short* Wl0b = (unsigned short*)(ws + o); o += (size_t)2 * 2048 * 320 * 2;
    unsigned short* Wl1b = (unsigned short*)(ws + o); o += (size_t)2 * 2048 * 1024 * 2;
    unsigned short* Wsh0 = (unsigned short*)(ws + o); o += (size_t)2 * 1048576 * 2;
    unsigned short* Wsh1 = (unsigned short*)(ws + o); o += (size_t)2 * 1048576 * 2;
    unsigned short* ws1b = (unsigned short*)(ws + o); o += (size_t)384 * 1024 * 2;
    unsigned short* ws2b = (unsigned short*)(ws + o); o += (size_t)16 * 384 * 2 + 192;
    unsigned short* capsT = (unsigned short*)(ws + o); o += (size_t)16 * 1024 * 1024 * 2;
    unsigned short* hbuf = (unsigned short*)(ws + o); o += (size_t)2 * 2 * 256 * 512 * 2;
    float* biasc = (float*)(ws + o); o += (size_t)4 * 2048 * 4;
    unsigned* cnts = (unsigned*)(ws + o); o += 256;
    // overlay region (inside ZxL, dead after layer-1 recurrence):
    unsigned short* hbarb = (unsigned short*)(ws + zx_off);
    float* att = (float*)(ws + zx_off + (size_t)16384 * 384 * 2);
    unsigned short* sentb = (unsigned short*)(ws + zx_off + (size_t)16384 * 384 * 2 + 1048576);
    float* votes = (float*)(ws + zx_off + (size_t)16384 * 384 * 2 + 1048576 + (size_t)256 * 16 * 1024 * 2);

    hipMemsetAsync(cnts, 0, 256, stream);

    k_embed<<<16384 * 320 / 256, 256, 0, stream>>>(tokens, embedding, Xb16);
    k_cvt_pad<<<(2048 * 320 + 255) / 256, 256, 0, stream>>>(Wih_l0f, Wl0b, 2048, 300, 2048, 320);
    k_cvt_pad<<<(2048 * 320 + 255) / 256, 256, 0, stream>>>(Wih_l0b, Wl0b + (size_t)2048 * 320, 2048, 300, 2048, 320);
    k_cvt_pad<<<(2048 * 1024 + 255) / 256, 256, 0, stream>>>(Wih_l1f, Wl1b, 2048, 1024, 2048, 1024);
    k_cvt_pad<<<(2048 * 1024 + 255) / 256, 256, 0, stream>>>(Wih_l1b, Wl1b + (size_t)2048 * 1024, 2048, 1024, 2048, 1024);
    k_cvt_pad<<<(384 * 1024 + 255) / 256, 256, 0, stream>>>(ws1, ws1b, 350, 1024, 384, 1024);
    k_cvt_pad<<<(16 * 384 + 255) / 256, 256, 0, stream>>>(ws2, ws2b, 16, 350, 16, 384);
    k_capsT<<<dim3(16, 32, 32), 256, 0, stream>>>(caps_W, capsT);
    k_whh_shuf<<<4096, 256, 0, stream>>>(Whh_l0f, Wsh0);
    k_whh_shuf<<<4096, 256, 0, stream>>>(Whh_l0b, Wsh0 + 1048576);
    k_whh_shuf<<<4096, 256, 0, stream>>>(Whh_l1f, Wsh1);
    k_whh_shuf<<<4096, 256, 0, stream>>>(Whh_l1b, Wsh1 + 1048576);
    hipMemcpyAsync(biasc + 0, b_l0f, 2048 * 4, hipMemcpyDeviceToDevice, stream);
    hipMemcpyAsync(biasc + 2048, b_l0b, 2048 * 4, hipMemcpyDeviceToDevice, stream);
    hipMemcpyAsync(biasc + 4096, b_l1f, 2048 * 4, hipMemcpyDeviceToDevice, stream);
    hipMemcpyAsync(biasc + 6144, b_l1b, 2048 * 4, hipMemcpyDeviceToDevice, stream);

    hipFuncSetAttribute(reinterpret_cast<const void*>(k_lstm),
                        hipFuncAttributeMaxDynamicSharedMemorySize, 147968);

    k_gemm<1, 0><<<dim3(128, 16, 2), 256, 0, stream>>>(
        Xb16, Wl0b, ZxL, biasc, 320, 320, 2048,
        0L, (long)2048 * 320, (long)16384 * 2048, 2048L);
    k_lstm<<<128, 256, 147968, stream>>>(ZxL, Wsh0, hbuf, L0, cnts);
    k_gemm<1, 0><<<dim3(128, 16, 2), 256, 0, stream>>>(
        L0, Wl1b, ZxL, biasc + 4096, 1024, 1024, 2048,
        0L, (long)2048 * 1024, (long)16384 * 2048, 2048L);
    k_lstm<<<128, 256, 147968, stream>>>(ZxL, Wsh1, hbuf, L1, cnts + 8);
    k_gemm<1, 1><<<dim3(128, 3, 1), 256, 0, stream>>>(
        L1, ws1b, hbarb, nullptr, 1024, 1024, 384, 0L, 0L, 0L, 0L);
    k_alphas<<<256, 256, 0, stream>>>(hbarb, ws2b, att);
    k_sent<<<dim3(256, 8), 256, 0, stream>>>(att, L1, out, sentb);
    k_gemm<0, 0><<<dim3(2, 8, 16), 256, 0, stream>>>(
        sentb, capsT, votes, nullptr, 1024, 16384, 16384,
        1024L, 1048576L, 1024L, 0L);
    k_route<<<256, 256, 0, stream>>>(votes, out + (size_t)4194304);
}

// Round 4
// 1754.670 us; speedup vs baseline: 1.7444x; 1.5430x over previous
//
#include <hip/hip_runtime.h>
#include <stdint.h>

// Problem constants
#define PB 256
#define PT 64
#define PE 300
#define PH 512
#define PDA 350
#define PR 16
#define PS 64
#define PA 16

typedef __attribute__((ext_vector_type(8))) short short8;
typedef __attribute__((ext_vector_type(4))) float f4;
typedef unsigned long long u64;

__device__ __forceinline__ float bf2f(unsigned short u) {
    unsigned v = ((unsigned)u) << 16;
    return __builtin_bit_cast(float, v);
}
__device__ __forceinline__ unsigned short f2bf(float f) {
    unsigned u = __builtin_bit_cast(unsigned int, f);
    u = u + 0x7fffu + ((u >> 16) & 1u);
    return (unsigned short)(u >> 16);
}
__device__ __forceinline__ float sigf(float x) { return 1.f / (1.f + __expf(-x)); }
__device__ __forceinline__ float tanhf_(float x) { return 1.f - 2.f / (1.f + __expf(2.f * x)); }

// ---------------- converters ----------------

__global__ __launch_bounds__(256) void k_embed(const int* __restrict__ tokens,
                                               const float* __restrict__ emb,
                                               unsigned short* __restrict__ X) {
    int idx = blockIdx.x * 256 + threadIdx.x;
    if (idx >= 16384 * 320) return;
    int row = idx / 320, e = idx - row * 320;
    int t = row >> 8, b = row & 255;
    float v = 0.f;
    if (e < 300) v = emb[(long)tokens[b * 64 + t] * 300 + e];
    X[idx] = f2bf(v);
}

__global__ __launch_bounds__(256) void k_cvt_pad(const float* __restrict__ src,
                                                 unsigned short* __restrict__ dst,
                                                 int N, int K, int N2, int K2) {
    int idx = blockIdx.x * 256 + threadIdx.x;
    if (idx >= N2 * K2) return;
    int n = idx / K2, k = idx - n * K2;
    float v = (n < N && k < K) ? src[(long)n * K + k] : 0.f;
    dst[idx] = f2bf(v);
}

__global__ __launch_bounds__(256) void k_capsT(const float* __restrict__ src,
                                               unsigned short* __restrict__ dst) {
    __shared__ float tile[32][33];
    int r = blockIdx.x, kb = blockIdx.y * 32, nb = blockIdx.z * 32;
    int tx = threadIdx.x & 31, ty = threadIdx.x >> 5;
    for (int i = 0; i < 32; i += 8)
        tile[ty + i][tx] = src[((long)r << 20) + (long)(kb + ty + i) * 1024 + nb + tx];
    __syncthreads();
    for (int i = 0; i < 32; i += 8)
        dst[((long)r << 20) + (long)(nb + ty + i) * 1024 + kb + tx] = f2bf(tile[tx][ty + i]);
}

__global__ __launch_bounds__(256) void k_whh_shuf(const float* __restrict__ W,
                                                  unsigned short* __restrict__ dst) {
    int idx = blockIdx.x * 256 + threadIdx.x;
    int el = idx & 7, lane = (idx >> 3) & 63, ks = (idx >> 9) & 15, nt = (idx >> 13) & 7, hs = idx >> 16;
    int gcol = (nt >> 1) * 512 + hs * 32 + (nt & 1) * 16 + (lane & 15);
    int k = ks * 32 + (lane >> 4) * 8 + el;
    dst[idx] = f2bf(W[(long)gcol * 512 + k]);
}

// ---------------- generic bf16 MFMA GEMM ----------------
template <int OUT_BF16, int TANH>
__global__ __launch_bounds__(256) void k_gemm(const unsigned short* __restrict__ A,
                                              const unsigned short* __restrict__ W,
                                              void* __restrict__ Cv,
                                              const float* __restrict__ bias,
                                              int K, int lda, int ldc,
                                              long aOffZ, long wOffZ, long cOffZ, long bOffZ) {
    A += blockIdx.z * aOffZ;
    W += blockIdx.z * wOffZ;
    if (bias) bias += blockIdx.z * bOffZ;
    const long cbase = blockIdx.z * cOffZ;
    const int m0 = blockIdx.x * 128, n0 = blockIdx.y * 128;
    __shared__ unsigned short As[4096], Bs[4096];
    const int w = threadIdx.x >> 6, l = threadIdx.x & 63;
    const int wm = w & 1, wn = w >> 1;
    const int fr = l & 15, fk = (l >> 4) * 8;
    f4 acc[4][4] = {};
    for (int k0 = 0; k0 < K; k0 += 32) {
        __syncthreads();
#pragma unroll
        for (int i = 0; i < 2; i++) {
            int tI = w + i * 4;
            const unsigned short* ga = A + (long)(m0 + tI * 16 + fr) * lda + k0 + fk;
            const unsigned short* gb = W + (long)(n0 + tI * 16 + fr) * K + k0 + fk;
            *(short8*)&As[tI * 512 + l * 8] = *(const short8*)ga;
            *(short8*)&Bs[tI * 512 + l * 8] = *(const short8*)gb;
        }
        __syncthreads();
        short8 av[4], bv[4];
#pragma unroll
        for (int mt = 0; mt < 4; mt++) av[mt] = *(short8*)&As[(wm * 4 + mt) * 512 + l * 8];
#pragma unroll
        for (int nt = 0; nt < 4; nt++) bv[nt] = *(short8*)&Bs[(wn * 4 + nt) * 512 + l * 8];
#pragma unroll
        for (int mt = 0; mt < 4; mt++)
#pragma unroll
            for (int nt = 0; nt < 4; nt++)
                acc[mt][nt] = __builtin_amdgcn_mfma_f32_16x16x32_bf16(av[mt], bv[nt], acc[mt][nt], 0, 0, 0);
    }
#pragma unroll
    for (int mt = 0; mt < 4; mt++) {
        int row = m0 + wm * 64 + mt * 16 + (l >> 4) * 4;
#pragma unroll
        for (int nt = 0; nt < 4; nt++) {
            int col = n0 + wn * 64 + nt * 16 + (l & 15);
            float bb = bias ? bias[col] : 0.f;
#pragma unroll
            for (int i = 0; i < 4; i++) {
                float v = acc[mt][nt][i] + bb;
                if (TANH) v = tanhf_(v);
                long off = cbase + (long)(row + i) * ldc + col;
                if (OUT_BF16)
                    ((unsigned short*)Cv)[off] = f2bf(v);
                else
                    ((float*)Cv)[off] = v;
            }
        }
    }
}

// ---------------- persistent bidirectional LSTM layer ----------------
// Per-step h buffers (hsteps[step][dir][256][512]): addresses are write-once/
// read-once within a dispatch, so consumers can use NORMAL cached loads (first
// touch misses the freshly-invalidated L2 and fetches from IF, where the
// producer's sc1 write-through stores landed). No fences, no L2 flushes.
//  writer: sc1 write-through stores -> vmcnt(0) -> barrier -> tid0 relaxed atomicAdd
//  reader: tid0 relaxed poll -> barrier -> plain loads
__global__ __launch_bounds__(256) void k_lstm(const unsigned short* __restrict__ Zx,
                                              const unsigned short* __restrict__ Wshuf,
                                              unsigned short* __restrict__ hsteps,
                                              unsigned short* __restrict__ Lout,
                                              unsigned* __restrict__ cnt) {
    extern __shared__ char smem[];
    unsigned short* Wl = (unsigned short*)smem;        // 128 KB
    float* zl = (float*)(smem + 131072);               // [32][132]
    const int bid = blockIdx.x;
    const int dir = bid >> 6, bg = (bid >> 4) & 3, hs = bid & 15;
    const int tid = threadIdx.x;
    const int l = tid & 63;
    const int w = tid >> 6;
    const int mt2 = w & 1, hc2 = w >> 1;

    // Whh slice into LDS (resident for all 64 steps)
    {
        const short8* src = (const short8*)(Wshuf + ((long)(dir * 16 + hs) << 16));
        short8* dst = (short8*)Wl;
        for (int i = tid; i < 8192; i += 256) dst[i] = src[i];
    }
    // zero step-0 h (write-through so cross-XCD readers see it at IF)
    {
        unsigned short* hz = hsteps + (long)dir * (256 * 512);
        for (int i = tid; i < 1024; i += 256) {
            int r = i >> 4, c2 = i & 15;
            __hip_atomic_store((unsigned*)&hz[(bg * 64 + r) * 512 + hs * 32 + c2 * 2], 0u,
                               __ATOMIC_RELAXED, __HIP_MEMORY_SCOPE_AGENT);
        }
    }
    unsigned* myc = cnt + (dir * 4 + bg) * 32;  // 128-B spacing: no line sharing
    asm volatile("s_waitcnt vmcnt(0)" ::: "memory");
    __syncthreads();
    if (tid == 0) __hip_atomic_fetch_add(myc, 1u, __ATOMIC_RELAXED, __HIP_MEMORY_SCOPE_AGENT);

    float c_reg[8];
#pragma unroll
    for (int i = 0; i < 8; i++) c_reg[i] = 0.f;

    const int pw_r[2] = { tid >> 4, 16 + (tid >> 4) };
    const int pw_c0 = (tid & 15) * 2;

    for (int step = 0; step < 64; step++) {
        const int t_eff = dir ? (63 - step) : step;
        const unsigned short* zbase = Zx + ((long)dir * 16384 + (long)t_eff * 256) * 2048;

        // prefetch Zx gate pairs (independent of h -> issue before poll)
        unsigned zpre[2][2][4];
#pragma unroll
        for (int half = 0; half < 2; half++)
#pragma unroll
            for (int k2 = 0; k2 < 2; k2++) {
                int rowg = bg * 64 + half * 32 + pw_r[k2];
                int jg = hs * 32 + pw_c0;
                const unsigned short* zrow = zbase + (long)rowg * 2048;
#pragma unroll
                for (int g = 0; g < 4; g++)
                    zpre[half][k2][g] = *(const unsigned*)&zrow[g * 512 + jg];
            }

        if (tid == 0) {
            unsigned target = 16u * (unsigned)(step + 1);
            while (__hip_atomic_load(myc, __ATOMIC_RELAXED, __HIP_MEMORY_SCOPE_AGENT) < target) {}
        }
        __syncthreads();

        // GEMM: h(rows of this wave) @ WhhT(slice); h via NORMAL cached loads,
        // register-prefetched one ks-iteration ahead.
        f4 acc[2][4] = {};
        const unsigned short* hb = hsteps + ((long)step * 2 + dir) * (256 * 512);
        const unsigned short* pa0 = hb + (bg * 64 + (mt2 * 2 + 0) * 16 + (l & 15)) * 512 + (l >> 4) * 8;
        const unsigned short* pa1 = hb + (bg * 64 + (mt2 * 2 + 1) * 16 + (l & 15)) * 512 + (l >> 4) * 8;
        short8 a0 = *(const short8*)pa0;
        short8 a1 = *(const short8*)pa1;
#pragma unroll
        for (int ks = 0; ks < 16; ks++) {
            short8 a0c = a0, a1c = a1;
            if (ks < 15) {
                a0 = *(const short8*)(pa0 + (ks + 1) * 32);
                a1 = *(const short8*)(pa1 + (ks + 1) * 32);
            }
#pragma unroll
            for (int s = 0; s < 4; s++) {
                int nt = s * 2 + hc2;
                short8 b = *(short8*)&Wl[((nt * 16 + ks) * 64 + l) * 8];
                acc[0][s] = __builtin_amdgcn_mfma_f32_16x16x32_bf16(a0c, b, acc[0][s], 0, 0, 0);
                acc[1][s] = __builtin_amdgcn_mfma_f32_16x16x32_bf16(a1c, b, acc[1][s], 0, 0, 0);
            }
        }

        unsigned short* hw = hsteps + ((long)(step + 1) * 2 + dir) * (256 * 512);
#pragma unroll
        for (int half = 0; half < 2; half++) {
            __syncthreads();
            if (mt2 == half) {
#pragma unroll
                for (int i2 = 0; i2 < 2; i2++) {
                    int rloc = i2 * 16 + (l >> 4) * 4;
#pragma unroll
                    for (int s = 0; s < 4; s++) {
                        int col = s * 32 + hc2 * 16 + (l & 15);
#pragma unroll
                        for (int i = 0; i < 4; i++) zl[(rloc + i) * 132 + col] = acc[i2][s][i];
                    }
                }
            }
            __syncthreads();
#pragma unroll
            for (int k2 = 0; k2 < 2; k2++) {
                int r = pw_r[k2];
                int c0 = pw_c0;
                int rowg = bg * 64 + half * 32 + r;
                int jg = hs * 32 + c0;
                unsigned ui = zpre[half][k2][0], uf = zpre[half][k2][1];
                unsigned ug = zpre[half][k2][2], uo = zpre[half][k2][3];
                float zi0 = zl[r * 132 + 0 * 32 + c0] + bf2f((unsigned short)ui);
                float zf0 = zl[r * 132 + 1 * 32 + c0] + bf2f((unsigned short)uf);
                float zg0 = zl[r * 132 + 2 * 32 + c0] + bf2f((unsigned short)ug);
                float zo0 = zl[r * 132 + 3 * 32 + c0] + bf2f((unsigned short)uo);
                float zi1 = zl[r * 132 + 0 * 32 + c0 + 1] + bf2f((unsigned short)(ui >> 16));
                float zf1 = zl[r * 132 + 1 * 32 + c0 + 1] + bf2f((unsigned short)(uf >> 16));
                float zg1 = zl[r * 132 + 2 * 32 + c0 + 1] + bf2f((unsigned short)(ug >> 16));
                float zo1 = zl[r * 132 + 3 * 32 + c0 + 1] + bf2f((unsigned short)(uo >> 16));
                int ci = half * 4 + k2 * 2;
                float ca = sigf(zf0) * c_reg[ci] + sigf(zi0) * tanhf_(zg0);
                c_reg[ci] = ca;
                float ha = sigf(zo0) * tanhf_(ca);
                float cb = sigf(zf1) * c_reg[ci + 1] + sigf(zi1) * tanhf_(zg1);
                c_reg[ci + 1] = cb;
                float hbv = sigf(zo1) * tanhf_(cb);
                unsigned pack = (unsigned)f2bf(ha) | ((unsigned)f2bf(hbv) << 16);
                __hip_atomic_store((unsigned*)&hw[(long)rowg * 512 + jg], pack,
                                   __ATOMIC_RELAXED, __HIP_MEMORY_SCOPE_AGENT);
                *(unsigned*)&Lout[((long)t_eff * 256 + rowg) * 1024 + dir * 512 + jg] = pack;
            }
        }
        asm volatile("s_waitcnt vmcnt(0)" ::: "memory");
        __syncthreads();
        if (tid == 0) __hip_atomic_fetch_add(myc, 1u, __ATOMIC_RELAXED, __HIP_MEMORY_SCOPE_AGENT);
    }
}

// ---------------- alphas ----------------
__global__ __launch_bounds__(256) void k_alphas(const unsigned short* __restrict__ hbar,
                                                const unsigned short* __restrict__ ws2,
                                                float* __restrict__ att) {
    int w = threadIdx.x >> 6, l = threadIdx.x & 63;
    int mtile = blockIdx.x * 4 + w;
    f4 acc = {};
    const unsigned short* arow = hbar + (long)(mtile * 16 + (l & 15)) * 384 + (l >> 4) * 8;
    const unsigned short* brow = ws2 + (long)(l & 15) * 384 + (l >> 4) * 8;
    for (int ks = 0; ks < 12; ks++) {
        short8 a = *(const short8*)&arow[ks * 32];
        short8 b = *(const short8*)&brow[ks * 32];
        acc = __builtin_amdgcn_mfma_f32_16x16x32_bf16(a, b, acc, 0, 0, 0);
    }
    int r = l & 15;
#pragma unroll
    for (int i = 0; i < 4; i++) {
        int bt = mtile * 16 + (l >> 4) * 4 + i;
        int b = bt & 255, t = bt >> 8;
        att[((long)b * 16 + r) * 64 + t] = acc[i];
    }
}

// ---------------- sent: each thread owns one n-col, 8 r-accumulators ----------------
__global__ __launch_bounds__(256) void k_sent(const float* __restrict__ att,
                                              const unsigned short* __restrict__ L1,
                                              float* __restrict__ sent,
                                              unsigned short* __restrict__ sentb) {
    int b = blockIdx.x, n0 = blockIdx.y * 128;
    __shared__ float al[1024];
    for (int i = threadIdx.x; i < 1024; i += 256) al[i] = att[(long)b * 1024 + i];
    __syncthreads();
    int n = n0 + (threadIdx.x & 127);
    int rh = (threadIdx.x >> 7) * 8;
    float acc[8] = {};
    for (int t = 0; t < 64; t++) {
        float x = bf2f(L1[((long)t * 256 + b) * 1024 + n]);
#pragma unroll
        for (int r = 0; r < 8; r++) acc[r] += al[(rh + r) * 64 + t] * x;
    }
#pragma unroll
    for (int r = 0; r < 8; r++) {
        long o = ((long)b * 16 + rh + r) * 1024 + n;
        sent[o] = acc[r];
        sentb[o] = f2bf(acc[r]);
    }
}

// ---------------- dynamic routing ----------------
__global__ __launch_bounds__(256) void k_route(const float* __restrict__ votes,
                                               float* __restrict__ clog) {
    __shared__ float v[16384];
    __shared__ float logits[1024];
    __shared__ float route[1024];
    __shared__ float pre[1024];
    __shared__ float act[1024];
    __shared__ float cl[64];
    int b = blockIdx.x, tid = threadIdx.x;
    for (int i = tid; i < 4096; i += 256) ((f4*)v)[i] = ((const f4*)(votes + (long)b * 16384))[i];
    for (int i = tid; i < 1024; i += 256) logits[i] = 0.f;
    __syncthreads();
    for (int it = 0; it < 3; it++) {
        if (tid < 16) {
            float m = -1e30f;
            for (int s = 0; s < 64; s++) m = fmaxf(m, logits[tid * 64 + s]);
            float sum = 0.f;
            for (int s = 0; s < 64; s++) {
                float e = __expf(logits[tid * 64 + s] - m);
                route[tid * 64 + s] = e;
                sum += e;
            }
            float inv = 1.f / sum;
            for (int s = 0; s < 64; s++) route[tid * 64 + s] *= inv;
        }
        __syncthreads();
#pragma unroll
        for (int k = 0; k < 4; k++) {
            int p = k * 256 + tid;
            int s = p >> 4, a = p & 15;
            float acc = 0.f;
            for (int r = 0; r < 16; r++) acc += route[r * 64 + s] * v[(r * 64 + s) * 16 + a];
            pre[p] = acc;
        }
        __syncthreads();
        if (tid < 64) {
            float nsq = 0.f;
            for (int a = 0; a < 16; a++) nsq += pre[tid * 16 + a] * pre[tid * 16 + a];
            float norm = sqrtf(nsq);
            float sc = norm / (0.5f + nsq);
            for (int a = 0; a < 16; a++) act[tid * 16 + a] = pre[tid * 16 + a] * sc;
            cl[tid] = nsq / (0.5f + nsq);
        }
        __syncthreads();
#pragma unroll
        for (int k = 0; k < 4; k++) {
            int p = k * 256 + tid;
            int r = p >> 6, s = p & 63;
            float acc = 0.f;
            for (int a = 0; a < 16; a++) acc += v[(r * 64 + s) * 16 + a] * act[s * 16 + a];
            logits[p] += acc;
        }
        __syncthreads();
    }
    if (tid < 64) clog[(long)b * 64 + tid] = cl[tid];
}

// ---------------- host ----------------
extern "C" void kernel_launch(void* const* d_in, const int* in_sizes, int n_in,
                              void* d_out, int out_size, void* d_ws, size_t ws_size,
                              hipStream_t stream) {
    const int* tokens = (const int*)d_in[0];
    const float* embedding = (const float*)d_in[2];
    const float* Wih_l0f = (const float*)d_in[3];
    const float* Whh_l0f = (const float*)d_in[4];
    const float* b_l0f = (const float*)d_in[5];
    const float* Wih_l0b = (const float*)d_in[6];
    const float* Whh_l0b = (const float*)d_in[7];
    const float* b_l0b = (const float*)d_in[8];
    const float* Wih_l1f = (const float*)d_in[9];
    const float* Whh_l1f = (const float*)d_in[10];
    const float* b_l1f = (const float*)d_in[11];
    const float* Wih_l1b = (const float*)d_in[12];
    const float* Whh_l1b = (const float*)d_in[13];
    const float* b_l1b = (const float*)d_in[14];
    const float* ws1 = (const float*)d_in[15];
    const float* ws2 = (const float*)d_in[16];
    const float* caps_W = (const float*)d_in[17];
    float* out = (float*)d_out;

    char* ws = (char*)d_ws;
    size_t o = 0;
    unsigned short* Xb16 = (unsigned short*)(ws + o); o += (size_t)16384 * 320 * 2;
    unsigned short* ZxL = (unsigned short*)(ws + o); size_t zx_off = o; o += (size_t)2 * 16384 * 2048 * 2;
    unsigned short* L0 = (unsigned short*)(ws + o); o += (size_t)16384 * 1024 * 2;
    unsigned short* L1 = (unsigned short*)(ws + o); o += (size_t)16384 * 1024 * 2;
    unsigned short* Wl0b = (unsigned short*)(ws + o); o += (size_t)2 * 2048 * 320 * 2;
    unsigned short* Wl1b = (unsigned short*)(ws + o); o += (size_t)2 * 2048 * 1024 * 2;
    unsigned short* Wsh0 = (unsigned short*)(ws + o); o += (size_t)2 * 1048576 * 2;
    unsigned short* Wsh1 = (unsigned short*)(ws + o); o += (size_t)2 * 1048576 * 2;
    unsigned short* ws1b = (unsigned short*)(ws + o); o += (size_t)384 * 1024 * 2;
    unsigned short* ws2b = (unsigned short*)(ws + o); o += (size_t)16 * 384 * 2 + 192;
    float* biasc = (float*)(ws + o); o += (size_t)4 * 2048 * 4;
    unsigned* cnts = (unsigned*)(ws + o); o += 4096;  // 2 layers x 8 groups x 128B
    // UNION region: hsteps (34.1 MB, live only during the two k_lstm dispatches)
    // and capsT (33.5 MB, written after layer-1 lstm, read by the votes GEMM).
    unsigned short* hsteps = (unsigned short*)(ws + o);
    unsigned short* capsT = (unsigned short*)(ws + o);
    o += (size_t)65 * 2 * 256 * 512 * 2;
    // overlay region (inside ZxL, dead after layer-1 recurrence):
    unsigned short* hbarb = (unsigned short*)(ws + zx_off);
    float* att = (float*)(ws + zx_off + (size_t)16384 * 384 * 2);
    unsigned short* sentb = (unsigned short*)(ws + zx_off + (size_t)16384 * 384 * 2 + 1048576);
    float* votes = (float*)(ws + zx_off + (size_t)16384 * 384 * 2 + 1048576 + (size_t)256 * 16 * 1024 * 2);

    hipMemsetAsync(cnts, 0, 4096, stream);

    k_embed<<<16384 * 320 / 256, 256, 0, stream>>>(tokens, embedding, Xb16);
    k_cvt_pad<<<(2048 * 320 + 255) / 256, 256, 0, stream>>>(Wih_l0f, Wl0b, 2048, 300, 2048, 320);
    k_cvt_pad<<<(2048 * 320 + 255) / 256, 256, 0, stream>>>(Wih_l0b, Wl0b + (size_t)2048 * 320, 2048, 300, 2048, 320);
    k_cvt_pad<<<(2048 * 1024 + 255) / 256, 256, 0, stream>>>(Wih_l1f, Wl1b, 2048, 1024, 2048, 1024);
    k_cvt_pad<<<(2048 * 1024 + 255) / 256, 256, 0, stream>>>(Wih_l1b, Wl1b + (size_t)2048 * 1024, 2048, 1024, 2048, 1024);
    k_cvt_pad<<<(384 * 1024 + 255) / 256, 256, 0, stream>>>(ws1, ws1b, 350, 1024, 384, 1024);
    k_cvt_pad<<<(16 * 384 + 255) / 256, 256, 0, stream>>>(ws2, ws2b, 16, 350, 16, 384);
    k_whh_shuf<<<4096, 256, 0, stream>>>(Whh_l0f, Wsh0);
    k_whh_shuf<<<4096, 256, 0, stream>>>(Whh_l0b, Wsh0 + 1048576);
    k_whh_shuf<<<4096, 256, 0, stream>>>(Whh_l1f, Wsh1);
    k_whh_shuf<<<4096, 256, 0, stream>>>(Whh_l1b, Wsh1 + 1048576);
    hipMemcpyAsync(biasc + 0, b_l0f, 2048 * 4, hipMemcpyDeviceToDevice, stream);
    hipMemcpyAsync(biasc + 2048, b_l0b, 2048 * 4, hipMemcpyDeviceToDevice, stream);
    hipMemcpyAsync(biasc + 4096, b_l1f, 2048 * 4, hipMemcpyDeviceToDevice, stream);
    hipMemcpyAsync(biasc + 6144, b_l1b, 2048 * 4, hipMemcpyDeviceToDevice, stream);

    hipFuncSetAttribute(reinterpret_cast<const void*>(k_lstm),
                        hipFuncAttributeMaxDynamicSharedMemorySize, 147968);

    k_gemm<1, 0><<<dim3(128, 16, 2), 256, 0, stream>>>(
        Xb16, Wl0b, ZxL, biasc, 320, 320, 2048,
        0L, (long)2048 * 320, (long)16384 * 2048, 2048L);
    k_lstm<<<128, 256, 147968, stream>>>(ZxL, Wsh0, hsteps, L0, cnts);
    k_gemm<1, 0><<<dim3(128, 16, 2), 256, 0, stream>>>(
        L0, Wl1b, ZxL, biasc + 4096, 1024, 1024, 2048,
        0L, (long)2048 * 1024, (long)16384 * 2048, 2048L);
    k_lstm<<<128, 256, 147968, stream>>>(ZxL, Wsh1, hsteps, L1, cnts + 256);
    // capsT conversion AFTER the lstms: its buffer aliases hsteps (dead now)
    k_capsT<<<dim3(16, 32, 32), 256, 0, stream>>>(caps_W, capsT);
    k_gemm<1, 1><<<dim3(128, 3, 1), 256, 0, stream>>>(
        L1, ws1b, hbarb, nullptr, 1024, 1024, 384, 0L, 0L, 0L, 0L);
    k_alphas<<<256, 256, 0, stream>>>(hbarb, ws2b, att);
    k_sent<<<dim3(256, 8), 256, 0, stream>>>(att, L1, out, sentb);
    k_gemm<0, 0><<<dim3(2, 8, 16), 256, 0, stream>>>(
        sentb, capsT, votes, nullptr, 1024, 16384, 16384,
        1024L, 1048576L, 1024L, 0L);
    k_route<<<256, 256, 0, stream>>>(votes, out + (size_t)4194304);
}